// Round 13
// baseline (134.627 us; speedup 1.0000x reference)
//
#include <hip/hip_runtime.h>

typedef unsigned short u16;
typedef unsigned int u32;
typedef __bf16 bf16x8 __attribute__((ext_vector_type(8)));
typedef float f32x4 __attribute__((ext_vector_type(4)));
typedef float f32x16 __attribute__((ext_vector_type(16)));
typedef int i32x2 __attribute__((ext_vector_type(2)));
typedef unsigned int u32x4 __attribute__((ext_vector_type(4)));

#define N_TOK 4096
#define DMODEL 1024
#define NH 16
#define DKH 64

__device__ inline u16 f2bf(float f){
  unsigned u = __float_as_uint(f);
  u += 0x7fffu + ((u >> 16) & 1u);
  return (u16)(u >> 16);
}

// raw v_exp_f32: args bounded (|x| < ~10), no libm guards needed
__device__ inline float fexp2(float x){ return __builtin_amdgcn_exp2f(x); }

// ---------- convert X (f32 -> bf16), vectorized ----------
__global__ __launch_bounds__(256) void k_convX(const float* __restrict__ X, u16* __restrict__ Xb){
  int i = blockIdx.x*256 + threadIdx.x;
  const float4 v = reinterpret_cast<const float4*>(X)[i];
  ushort4 o; o.x=f2bf(v.x); o.y=f2bf(v.y); o.z=f2bf(v.z); o.w=f2bf(v.w);
  reinterpret_cast<ushort4*>(Xb)[i] = o;
}

// ---------- transpose+convert W [1024][2048] f32 -> Wt [2048][1024] bf16 ----------
__global__ __launch_bounds__(256) void k_convW(const float* __restrict__ W, u16* __restrict__ Wt){
  __shared__ float tile[64][65];
  const int bn = blockIdx.x*64;
  const int bk = blockIdx.y*64;
  const int t = threadIdx.x;
  const int c4 = (t & 15)*4;
  const int r  = t >> 4;
  #pragma unroll
  for (int i=0;i<4;i++){
    int k = r + i*16;
    const float4 v = *reinterpret_cast<const float4*>(&W[(size_t)(bk+k)*2048 + bn + c4]);
    tile[k][c4+0]=v.x; tile[k][c4+1]=v.y; tile[k][c4+2]=v.z; tile[k][c4+3]=v.w;
  }
  __syncthreads();
  #pragma unroll
  for (int i=0;i<4;i++){
    int n = r + i*16;
    ushort4 o;
    o.x = f2bf(tile[c4+0][n]);
    o.y = f2bf(tile[c4+1][n]);
    o.z = f2bf(tile[c4+2][n]);
    o.w = f2bf(tile[c4+3][n]);
    *reinterpret_cast<ushort4*>(&Wt[(size_t)(bn+n)*1024 + bk + c4]) = o;
  }
}

// ---------- GEMM v2: BK=64, source-swizzled staging (round-9, proven) ----------
__global__ __launch_bounds__(256) void k_gemm(const u16* __restrict__ A, const u16* __restrict__ B,
                                              u16* __restrict__ kf_g, u16* __restrict__ vf_g){
  __shared__ alignas(16) u16 As[128*64];
  __shared__ alignas(16) u16 Bs[128*64];
  const int bm = blockIdx.y*128, bn = blockIdx.x*128;
  const int tid = threadIdx.x, wid = tid>>6, lane = tid&63;
  const int wr = wid>>1, wc = wid&1;
  const int lr = lane&15, lg = lane>>4;
  f32x4 acc[4][4] = {};

  for (int kk=0; kk<DMODEL; kk+=64){
    __syncthreads();
    #pragma unroll
    for (int i=0;i<4;i++){
      const int chunk = (wid*4+i)*64 + lane;          // 0..1023, 16B each
      const int row = chunk>>3, koc = chunk&7;
      const int swz = koc ^ (row&7);                  // pre-swizzle SOURCE; LDS dest linear
      const u16* ga = A + (size_t)(bm+row)*DMODEL + kk + swz*8;
      const u16* gb = B + (size_t)(bn+row)*DMODEL + kk + swz*8;
      __builtin_amdgcn_global_load_lds((const __attribute__((address_space(1))) void*)ga,
          (__attribute__((address_space(3))) void*)(&As[(size_t)chunk*8]), 16, 0, 0);
      __builtin_amdgcn_global_load_lds((const __attribute__((address_space(1))) void*)gb,
          (__attribute__((address_space(3))) void*)(&Bs[(size_t)chunk*8]), 16, 0, 0);
    }
    asm volatile("s_waitcnt vmcnt(0)" ::: "memory");
    __syncthreads();
    #pragma unroll
    for (int ks=0; ks<2; ks++){
      bf16x8 af[4], bfr[4];
      #pragma unroll
      for (int m=0;m<4;m++){
        const int row = wr*64+m*16+lr, cr = ks*4+lg;
        af[m] = *reinterpret_cast<const bf16x8*>(&As[(size_t)(row*8 + (cr ^ (row&7)))*8]);
      }
      #pragma unroll
      for (int n=0;n<4;n++){
        const int row = wc*64+n*16+lr, cr = ks*4+lg;
        bfr[n] = *reinterpret_cast<const bf16x8*>(&Bs[(size_t)(row*8 + (cr ^ (row&7)))*8]);
      }
      #pragma unroll
      for (int m=0;m<4;m++)
        #pragma unroll
        for (int n=0;n<4;n++)
          acc[m][n] = __builtin_amdgcn_mfma_f32_16x16x32_bf16(af[m], bfr[n], acc[m][n], 0,0,0);
    }
  }

  #pragma unroll
  for (int m=0;m<4;m++){
    const int row0 = bm + wr*64 + m*16 + lg*4;
    #pragma unroll
    for (int n=0;n<4;n++){
      const int c = bn + wc*64 + n*16 + lr;
      if (c < DMODEL){
        const int hh = c>>6, d = c&63;
        const size_t base = ((size_t)hh*512 + (size_t)(row0>>5)*4 + (d>>4))*512;
        #pragma unroll
        for (int r=0;r<4;r++){
          const int row = row0 + r;
          kf_g[base + (size_t)(((row&31) | (((d>>3)&1)<<5)))*8 + (d&7)] = f2bf(acc[m][n][r]);
        }
      } else {
        const int cc = c - DMODEL; const int hh = cc>>6, d = cc&63;
        const size_t base = (((size_t)hh*64 + (row0>>6))*8 + (d>>5)*4 + ((row0>>4)&3))*512
                          + (size_t)(((d&31) | (((row0>>3)&1)<<5)))*8 + (row0&7);
        ushort4 o;
        o.x = f2bf(acc[m][n][0]); o.y = f2bf(acc[m][n][1]);
        o.z = f2bf(acc[m][n][2]); o.w = f2bf(acc[m][n][3]);
        *reinterpret_cast<ushort4*>(&vf_g[base]) = o;
      }
    }
  }
}

// scale a bf16x8 fragment by s (unpack, multiply, repack RNE)
__device__ inline bf16x8 scale_bf8(bf16x8 v, float s){
  u32x4 w = __builtin_bit_cast(u32x4, v);
  u32x4 r;
  #pragma unroll
  for (int i=0;i<4;i++){
    float lo = __uint_as_float(w[i] << 16) * s;
    float hi = __uint_as_float(w[i] & 0xffff0000u) * s;
    u32 p;
    asm("v_cvt_pk_bf16_f32 %0, %1, %2" : "=v"(p) : "v"(lo), "v"(hi));
    r[i] = p;
  }
  return __builtin_bit_cast(bf16x8, r);
}

// ---------- flash attention v12: 32-key steps + rotating single-buffer K prefetch
// (r12's occupancy band ~116 unified regs kept; r10's latency hiding regained). ----------
__global__ __launch_bounds__(256,3) void k_attn(const u16* __restrict__ kf_g, const u16* __restrict__ vf_g,
                                                float* __restrict__ out){
  __shared__ float comb[3][64][17];
  const int bid  = blockIdx.x;
  const int xcd  = bid & 7;
  const int slot = bid >> 3;
  const int h    = (xcd<<1) | (slot>>7);
  const int qt   = slot & 127;
  const int wid  = threadIdx.x >> 6;
  const int lane = threadIdx.x & 63;
  const int ql   = lane & 31;
  const int q0   = qt*32;
  const u16* __restrict__ Kfh = kf_g + (size_t)h*262144;
  const u16* __restrict__ Vfh = vf_g + (size_t)h*262144;
  const float SC = 0.18033688011112042f;   // log2(e)/sqrt(64)

  bf16x8 qb[4];
  #pragma unroll
  for (int ds=0; ds<4; ds++){
    bf16x8 raw = *reinterpret_cast<const bf16x8*>(&Kfh[(size_t)((q0>>5)*4 + ds)*512 + lane*8]);
    qb[ds] = scale_bf8(raw, SC);
  }

  f32x16 o0 = {}, o1 = {};
  float lp = 0.f;
  const int kb = wid*1024;                 // this wave's 1024 keys

  bf16x8 kf[4];                            // rotating prefetch buffer (16 regs)
  auto loadK4 = [&](int kt){
    const u16* kp = Kfh + ((size_t)(kt>>5)*4)*512 + lane*8;
    kf[0] = *reinterpret_cast<const bf16x8*>(kp);
    kf[1] = *reinterpret_cast<const bf16x8*>(kp + 512);
    kf[2] = *reinterpret_cast<const bf16x8*>(kp + 1024);
    kf[3] = *reinterpret_cast<const bf16x8*>(kp + 1536);
  };

  loadK4(kb);
  for (int s=0; s<32; ++s){
    const int kt = kb + s*32;

    // QK^T (swapped) with prefetched K; then rotate-prefetch next step's K
    f32x16 p = {};
    p = __builtin_amdgcn_mfma_f32_32x32x16_bf16(kf[0], qb[0], p, 0,0,0);
    p = __builtin_amdgcn_mfma_f32_32x32x16_bf16(kf[1], qb[1], p, 0,0,0);
    p = __builtin_amdgcn_mfma_f32_32x32x16_bf16(kf[2], qb[2], p, 0,0,0);
    p = __builtin_amdgcn_mfma_f32_32x32x16_bf16(kf[3], qb[3], p, 0,0,0);
    loadK4(kb + (((s+1)&31)<<5));          // anti-dep: issues after QK reads; covered by exp/pack/PV

    // V fragments JIT (consumed after softmax; self-hiding)
    const u16* vb = Vfh + ((size_t)((kt>>6)*8 + (s&1)*2))*512 + lane*8;
    bf16x8 va0 = *reinterpret_cast<const bf16x8*>(vb);
    bf16x8 va1 = *reinterpret_cast<const bf16x8*>(vb + 512);
    bf16x8 vb0 = *reinterpret_cast<const bf16x8*>(vb + 4*512);
    bf16x8 vb1 = *reinterpret_cast<const bf16x8*>(vb + 5*512);

    // static-normalizer softmax (Q prescaled by SC)
    #pragma unroll
    for (int c=0; c<16; c++) p[c] = fexp2(p[c]);
    {
      float r0 = ((p[0]+p[1])+(p[2]+p[3])) + ((p[4]+p[5])+(p[6]+p[7]));
      float r1 = ((p[8]+p[9])+(p[10]+p[11])) + ((p[12]+p[13])+(p[14]+p[15]));
      lp += r0+r1;
    }

    // P -> bf16 B-fragments in registers
    u32 pk[8];
    #pragma unroll
    for (int c2=0; c2<8; c2++){
      u32 a;
      asm("v_cvt_pk_bf16_f32 %0, %1, %2" : "=v"(a) : "v"(p[2*c2]), "v"(p[2*c2+1]));
      pk[c2] = a;
    }
    // PV (swapped): two 16-key sub-steps
    #pragma unroll
    for (int t2=0; t2<2; t2++){
      const int base = 4*t2;
      i32x2 r0s = __builtin_amdgcn_permlane32_swap((int)pk[base+0], (int)pk[base+2], false, false);
      i32x2 r1s = __builtin_amdgcn_permlane32_swap((int)pk[base+1], (int)pk[base+3], false, false);
      u32x4 w; w[0] = (u32)r0s[0]; w[1] = (u32)r1s[0]; w[2] = (u32)r0s[1]; w[3] = (u32)r1s[1];
      bf16x8 bt = __builtin_bit_cast(bf16x8, w);
      o0 = __builtin_amdgcn_mfma_f32_32x32x16_bf16(t2 ? va1 : va0, bt, o0, 0,0,0);
      o1 = __builtin_amdgcn_mfma_f32_32x32x16_bf16(t2 ? vb1 : vb0, bt, o1, 0,0,0);
    }
  }

  lp += __shfl_xor(lp, 32, 64);

  // two-phase split-K combine (13 KB LDS)
  if (wid){
    float* c = &comb[wid-1][lane][0];
    #pragma unroll
    for (int g=0; g<16; g++) c[g] = o0[g];
    c[16] = lp;
  }
  __syncthreads();
  if (!wid){
    #pragma unroll
    for (int w=0; w<3; w++){
      const float* c = &comb[w][lane][0];
      #pragma unroll
      for (int g=0; g<16; g++) o0[g] += c[g];
      lp += c[16];
    }
  }
  __syncthreads();
  if (wid){
    float* c = &comb[wid-1][lane][0];
    #pragma unroll
    for (int g=0; g<16; g++) c[g] = o1[g];
  }
  __syncthreads();
  if (!wid){
    #pragma unroll
    for (int w=0; w<3; w++){
      const float* c = &comb[w][lane][0];
      #pragma unroll
      for (int g=0; g<16; g++) o1[g] += c[g];
    }
    const int hi = lane >> 5;
    const float inv = 1.f / lp;
    float* orow = out + (size_t)(q0 + ql)*DMODEL + h*DKH;
    #pragma unroll
    for (int g=0; g<4; g++){
      float4 s0, s1;
      s0.x = o0[4*g+0]*inv; s0.y = o0[4*g+1]*inv; s0.z = o0[4*g+2]*inv; s0.w = o0[4*g+3]*inv;
      s1.x = o1[4*g+0]*inv; s1.y = o1[4*g+1]*inv; s1.z = o1[4*g+2]*inv; s1.w = o1[4*g+3]*inv;
      *reinterpret_cast<float4*>(&orow[      8*g + 4*hi]) = s0;
      *reinterpret_cast<float4*>(&orow[32 +  8*g + 4*hi]) = s1;
    }
  }
}

extern "C" void kernel_launch(void* const* d_in, const int* in_sizes, int n_in,
                              void* d_out, int out_size, void* d_ws, size_t ws_size,
                              hipStream_t stream) {
  const float* X = (const float*)d_in[0];
  const float* W = (const float*)d_in[1];
  float* out = (float*)d_out;
  u16* Xb = (u16*)d_ws;                         //  8 MB
  u16* Wt = Xb + (size_t)N_TOK*DMODEL;          //  4 MB
  u16* Kf = Wt + (size_t)2*DMODEL*DMODEL;       //  8 MB fragment-major K/Q
  u16* Vf = Kf + (size_t)N_TOK*DMODEL;          //  8 MB fragment-major V^T

  k_convX<<<dim3(4096), dim3(256), 0, stream>>>(X, Xb);
  k_convW<<<dim3(32,16), dim3(256), 0, stream>>>(W, Wt);
  k_gemm <<<dim3(16,32), dim3(256), 0, stream>>>(Xb, Wt, Kf, Vf);
  k_attn <<<dim3(2048), dim3(256), 0, stream>>>(Kf, Vf, out);
}

// Round 14
// 118.190 us; speedup vs baseline: 1.1391x; 1.1391x over previous
//
#include <hip/hip_runtime.h>

typedef unsigned short u16;
typedef unsigned int u32;
typedef __bf16 bf16x8 __attribute__((ext_vector_type(8)));
typedef float f32x4 __attribute__((ext_vector_type(4)));
typedef float f32x16 __attribute__((ext_vector_type(16)));
typedef int i32x2 __attribute__((ext_vector_type(2)));
typedef unsigned int u32x4 __attribute__((ext_vector_type(4)));

#define N_TOK 4096
#define DMODEL 1024
#define NH 16
#define DKH 64

__device__ inline u16 f2bf(float f){
  unsigned u = __float_as_uint(f);
  u += 0x7fffu + ((u >> 16) & 1u);
  return (u16)(u >> 16);
}

// raw v_exp_f32: args bounded (|x| < ~10), no libm guards needed
__device__ inline float fexp2(float x){ return __builtin_amdgcn_exp2f(x); }

// ---------- convert X (f32 -> bf16), vectorized ----------
__global__ __launch_bounds__(256) void k_convX(const float* __restrict__ X, u16* __restrict__ Xb){
  int i = blockIdx.x*256 + threadIdx.x;
  const float4 v = reinterpret_cast<const float4*>(X)[i];
  ushort4 o; o.x=f2bf(v.x); o.y=f2bf(v.y); o.z=f2bf(v.z); o.w=f2bf(v.w);
  reinterpret_cast<ushort4*>(Xb)[i] = o;
}

// ---------- transpose+convert W [1024][2048] f32 -> Wt [2048][1024] bf16 ----------
__global__ __launch_bounds__(256) void k_convW(const float* __restrict__ W, u16* __restrict__ Wt){
  __shared__ float tile[64][65];
  const int bn = blockIdx.x*64;
  const int bk = blockIdx.y*64;
  const int t = threadIdx.x;
  const int c4 = (t & 15)*4;
  const int r  = t >> 4;
  #pragma unroll
  for (int i=0;i<4;i++){
    int k = r + i*16;
    const float4 v = *reinterpret_cast<const float4*>(&W[(size_t)(bk+k)*2048 + bn + c4]);
    tile[k][c4+0]=v.x; tile[k][c4+1]=v.y; tile[k][c4+2]=v.z; tile[k][c4+3]=v.w;
  }
  __syncthreads();
  #pragma unroll
  for (int i=0;i<4;i++){
    int n = r + i*16;
    ushort4 o;
    o.x = f2bf(tile[c4+0][n]);
    o.y = f2bf(tile[c4+1][n]);
    o.z = f2bf(tile[c4+2][n]);
    o.w = f2bf(tile[c4+3][n]);
    *reinterpret_cast<ushort4*>(&Wt[(size_t)(bn+n)*1024 + bk + c4]) = o;
  }
}

// ---------- GEMM v2: BK=64, source-swizzled staging (round-9, proven) ----------
__global__ __launch_bounds__(256) void k_gemm(const u16* __restrict__ A, const u16* __restrict__ B,
                                              u16* __restrict__ kf_g, u16* __restrict__ vf_g){
  __shared__ alignas(16) u16 As[128*64];
  __shared__ alignas(16) u16 Bs[128*64];
  const int bm = blockIdx.y*128, bn = blockIdx.x*128;
  const int tid = threadIdx.x, wid = tid>>6, lane = tid&63;
  const int wr = wid>>1, wc = wid&1;
  const int lr = lane&15, lg = lane>>4;
  f32x4 acc[4][4] = {};

  for (int kk=0; kk<DMODEL; kk+=64){
    __syncthreads();
    #pragma unroll
    for (int i=0;i<4;i++){
      const int chunk = (wid*4+i)*64 + lane;          // 0..1023, 16B each
      const int row = chunk>>3, koc = chunk&7;
      const int swz = koc ^ (row&7);                  // pre-swizzle SOURCE; LDS dest linear
      const u16* ga = A + (size_t)(bm+row)*DMODEL + kk + swz*8;
      const u16* gb = B + (size_t)(bn+row)*DMODEL + kk + swz*8;
      __builtin_amdgcn_global_load_lds((const __attribute__((address_space(1))) void*)ga,
          (__attribute__((address_space(3))) void*)(&As[(size_t)chunk*8]), 16, 0, 0);
      __builtin_amdgcn_global_load_lds((const __attribute__((address_space(1))) void*)gb,
          (__attribute__((address_space(3))) void*)(&Bs[(size_t)chunk*8]), 16, 0, 0);
    }
    asm volatile("s_waitcnt vmcnt(0)" ::: "memory");
    __syncthreads();
    #pragma unroll
    for (int ks=0; ks<2; ks++){
      bf16x8 af[4], bfr[4];
      #pragma unroll
      for (int m=0;m<4;m++){
        const int row = wr*64+m*16+lr, cr = ks*4+lg;
        af[m] = *reinterpret_cast<const bf16x8*>(&As[(size_t)(row*8 + (cr ^ (row&7)))*8]);
      }
      #pragma unroll
      for (int n=0;n<4;n++){
        const int row = wc*64+n*16+lr, cr = ks*4+lg;
        bfr[n] = *reinterpret_cast<const bf16x8*>(&Bs[(size_t)(row*8 + (cr ^ (row&7)))*8]);
      }
      #pragma unroll
      for (int m=0;m<4;m++)
        #pragma unroll
        for (int n=0;n<4;n++)
          acc[m][n] = __builtin_amdgcn_mfma_f32_16x16x32_bf16(af[m], bfr[n], acc[m][n], 0,0,0);
    }
  }

  #pragma unroll
  for (int m=0;m<4;m++){
    const int row0 = bm + wr*64 + m*16 + lg*4;
    #pragma unroll
    for (int n=0;n<4;n++){
      const int c = bn + wc*64 + n*16 + lr;
      if (c < DMODEL){
        const int hh = c>>6, d = c&63;
        const size_t base = ((size_t)hh*512 + (size_t)(row0>>5)*4 + (d>>4))*512;
        #pragma unroll
        for (int r=0;r<4;r++){
          const int row = row0 + r;
          kf_g[base + (size_t)(((row&31) | (((d>>3)&1)<<5)))*8 + (d&7)] = f2bf(acc[m][n][r]);
        }
      } else {
        const int cc = c - DMODEL; const int hh = cc>>6, d = cc&63;
        const size_t base = (((size_t)hh*64 + (row0>>6))*8 + (d>>5)*4 + ((row0>>4)&3))*512
                          + (size_t)(((d&31) | (((row0>>3)&1)<<5)))*8 + (row0&7);
        ushort4 o;
        o.x = f2bf(acc[m][n][0]); o.y = f2bf(acc[m][n][1]);
        o.z = f2bf(acc[m][n][2]); o.w = f2bf(acc[m][n][3]);
        *reinterpret_cast<ushort4*>(&vf_g[base]) = o;
      }
    }
  }
}

// scale a bf16x8 fragment by s (unpack, multiply, repack RNE)
__device__ inline bf16x8 scale_bf8(bf16x8 v, float s){
  u32x4 w = __builtin_bit_cast(u32x4, v);
  u32x4 r;
  #pragma unroll
  for (int i=0;i<4;i++){
    float lo = __uint_as_float(w[i] << 16) * s;
    float hi = __uint_as_float(w[i] & 0xffff0000u) * s;
    u32 p;
    asm("v_cvt_pk_bf16_f32 %0, %1, %2" : "=v"(p) : "v"(lo), "v"(hi));
    r[i] = p;
  }
  return __builtin_bit_cast(bf16x8, r);
}

// ---------- flash attention v13: block-cooperative LDS-staged K/V (4x L2 traffic cut).
// Block = 128 q-rows x 1 head (4 waves x 32q), no split-K. 128-key tiles double-buffered
// in LDS (2 x 32 KB), staged via global_load_lds, consumed by all 4 waves.
// Per-32-key step body identical to r12 (proven); K/V reads now from LDS. ----------
__global__ __launch_bounds__(256,2) void k_attn(const u16* __restrict__ kf_g, const u16* __restrict__ vf_g,
                                                float* __restrict__ out){
  __shared__ alignas(16) u16 stg[2][16384];   // [buf][K: chunks 0..15 | V: chunks 16..31], 32 KB each
  const int bid  = blockIdx.x;
  const int xcd  = bid & 7;
  const int slot = bid >> 3;              // 0..63
  const int h    = (xcd<<1) | (slot>>5);  // 2 heads per XCD
  const int qt   = slot & 31;
  const int wid  = threadIdx.x >> 6;
  const int lane = threadIdx.x & 63;
  const int ql   = lane & 31;
  const int q0   = qt*128 + wid*32;
  const u16* __restrict__ Kfh = kf_g + (size_t)h*262144;
  const u16* __restrict__ Vfh = vf_g + (size_t)h*262144;
  const float SC = 0.18033688011112042f;   // log2(e)/sqrt(64)

  bf16x8 qb[4];
  #pragma unroll
  for (int ds=0; ds<4; ds++){
    bf16x8 raw = *reinterpret_cast<const bf16x8*>(&Kfh[(size_t)((q0>>5)*4 + ds)*512 + lane*8]);
    qb[ds] = scale_bf8(raw, SC);
  }

  f32x16 o0 = {}, o1 = {};
  float lp = 0.f;

  // stage tile t (128 keys = 16 K-chunks + 16 V-chunks of 1 KB) into stg[buf]
  auto stage = [&](int buf, int t){
    #pragma unroll
    for (int i=0; i<8; i++){
      const int c = wid + i*4;             // 0..31, wave-uniform
      const u16* src = (c < 16)
        ? Kfh + ((size_t)(t*16 + c))*512 + lane*8
        : Vfh + ((size_t)(t*16 + c - 16))*512 + lane*8;
      __builtin_amdgcn_global_load_lds((const __attribute__((address_space(1))) void*)src,
          (__attribute__((address_space(3))) void*)(&stg[buf][(size_t)c*512]), 16, 0, 0);
    }
  };

  stage(0, 0);
  int cur = 0;
  for (int t=0; t<32; ++t){
    asm volatile("s_waitcnt vmcnt(0)" ::: "memory");
    __syncthreads();                       // tile t ready in stg[cur]
    if (t < 31) stage(cur^1, t+1);         // async prefetch next tile

    const u16* kb = &stg[cur][0];
    #pragma unroll
    for (int ss=0; ss<4; ++ss){
      // K fragments from LDS (local chunk ss*4+ds; lane-linear, conflict-free)
      bf16x8 kf0 = *reinterpret_cast<const bf16x8*>(&kb[(size_t)(ss*4+0)*512 + lane*8]);
      bf16x8 kf1 = *reinterpret_cast<const bf16x8*>(&kb[(size_t)(ss*4+1)*512 + lane*8]);
      bf16x8 kf2 = *reinterpret_cast<const bf16x8*>(&kb[(size_t)(ss*4+2)*512 + lane*8]);
      bf16x8 kf3 = *reinterpret_cast<const bf16x8*>(&kb[(size_t)(ss*4+3)*512 + lane*8]);

      f32x16 p = {};
      p = __builtin_amdgcn_mfma_f32_32x32x16_bf16(kf0, qb[0], p, 0,0,0);
      p = __builtin_amdgcn_mfma_f32_32x32x16_bf16(kf1, qb[1], p, 0,0,0);
      p = __builtin_amdgcn_mfma_f32_32x32x16_bf16(kf2, qb[2], p, 0,0,0);
      p = __builtin_amdgcn_mfma_f32_32x32x16_bf16(kf3, qb[3], p, 0,0,0);

      // V fragments from LDS: local chunk u*8 + dt*4 + (ss&1)*2 + t2, V base = chunk 16
      const int vbase = 8192 + ((ss>>1)*8 + (ss&1)*2)*512;
      bf16x8 va0 = *reinterpret_cast<const bf16x8*>(&kb[(size_t)vbase          + lane*8]);
      bf16x8 va1 = *reinterpret_cast<const bf16x8*>(&kb[(size_t)vbase +   512  + lane*8]);
      bf16x8 vb0 = *reinterpret_cast<const bf16x8*>(&kb[(size_t)vbase + 4*512  + lane*8]);
      bf16x8 vb1 = *reinterpret_cast<const bf16x8*>(&kb[(size_t)vbase + 5*512  + lane*8]);

      // static-normalizer softmax (Q prescaled by SC)
      #pragma unroll
      for (int c=0; c<16; c++) p[c] = fexp2(p[c]);
      {
        float r0 = ((p[0]+p[1])+(p[2]+p[3])) + ((p[4]+p[5])+(p[6]+p[7]));
        float r1 = ((p[8]+p[9])+(p[10]+p[11])) + ((p[12]+p[13])+(p[14]+p[15]));
        lp += r0+r1;
      }

      // P -> bf16 B-fragments in registers
      u32 pk[8];
      #pragma unroll
      for (int c2=0; c2<8; c2++){
        u32 a;
        asm("v_cvt_pk_bf16_f32 %0, %1, %2" : "=v"(a) : "v"(p[2*c2]), "v"(p[2*c2+1]));
        pk[c2] = a;
      }
      // PV (swapped): two 16-key sub-steps
      #pragma unroll
      for (int t2=0; t2<2; t2++){
        const int base = 4*t2;
        i32x2 r0s = __builtin_amdgcn_permlane32_swap((int)pk[base+0], (int)pk[base+2], false, false);
        i32x2 r1s = __builtin_amdgcn_permlane32_swap((int)pk[base+1], (int)pk[base+3], false, false);
        u32x4 w; w[0] = (u32)r0s[0]; w[1] = (u32)r1s[0]; w[2] = (u32)r0s[1]; w[3] = (u32)r1s[1];
        bf16x8 bt = __builtin_bit_cast(bf16x8, w);
        o0 = __builtin_amdgcn_mfma_f32_32x32x16_bf16(t2 ? va1 : va0, bt, o0, 0,0,0);
        o1 = __builtin_amdgcn_mfma_f32_32x32x16_bf16(t2 ? vb1 : vb0, bt, o1, 0,0,0);
      }
    }
    __syncthreads();                       // all waves done reading stg[cur]
    cur ^= 1;
  }

  lp += __shfl_xor(lp, 32, 64);

  // epilogue: every wave writes its own 32 q-rows (no split-K combine)
  const int hi = lane >> 5;
  const float inv = 1.f / lp;
  float* orow = out + (size_t)(q0 + ql)*DMODEL + h*DKH;
  #pragma unroll
  for (int g=0; g<4; g++){
    float4 s0, s1;
    s0.x = o0[4*g+0]*inv; s0.y = o0[4*g+1]*inv; s0.z = o0[4*g+2]*inv; s0.w = o0[4*g+3]*inv;
    s1.x = o1[4*g+0]*inv; s1.y = o1[4*g+1]*inv; s1.z = o1[4*g+2]*inv; s1.w = o1[4*g+3]*inv;
    *reinterpret_cast<float4*>(&orow[      8*g + 4*hi]) = s0;
    *reinterpret_cast<float4*>(&orow[32 +  8*g + 4*hi]) = s1;
  }
}

extern "C" void kernel_launch(void* const* d_in, const int* in_sizes, int n_in,
                              void* d_out, int out_size, void* d_ws, size_t ws_size,
                              hipStream_t stream) {
  const float* X = (const float*)d_in[0];
  const float* W = (const float*)d_in[1];
  float* out = (float*)d_out;
  u16* Xb = (u16*)d_ws;                         //  8 MB
  u16* Wt = Xb + (size_t)N_TOK*DMODEL;          //  4 MB
  u16* Kf = Wt + (size_t)2*DMODEL*DMODEL;       //  8 MB fragment-major K/Q
  u16* Vf = Kf + (size_t)N_TOK*DMODEL;          //  8 MB fragment-major V^T

  k_convX<<<dim3(4096), dim3(256), 0, stream>>>(X, Xb);
  k_convW<<<dim3(32,16), dim3(256), 0, stream>>>(W, Wt);
  k_gemm <<<dim3(16,32), dim3(256), 0, stream>>>(Xb, Wt, Kf, Vf);
  k_attn <<<dim3(512), dim3(256), 0, stream>>>(Kf, Vf, out);
}